// Round 2
// baseline (1091.694 us; speedup 1.0000x reference)
//
#include <hip/hip_runtime.h>
#include <hip/hip_bf16.h>

// Multi-LoRA fused: out[b,n,o] = (1/64) * sum_r ( sum_i x[b,n,i]*B[aid,r,i] ) * A[aid,o,r]
// x: [16,2048,4096] f32, ids: [16] int32, A: [64,4096,64] f32, B: [64,64,4096] f32
// out: [16,2048,4096] f32
//
// R2 changes vs R1 (411us/dispatch, latency-bound, all pipes idle):
//  - Stage 1: TRUE counted-vmcnt pipeline. B prefetched into REGISTERS one step
//    ahead, x two steps ahead. Consumption order guarantees the compiler's
//    vmcnt waits are vmcnt(4)/vmcnt(12)-style (loads issued a full iteration
//    earlier) -- never drains in-flight prefetches. R1's bug: B was loaded and
//    consumed in-iteration, so its vmcnt wait drained the x prefetch too.
//  - Stage 2: operand-SWAPPED MFMA (mfma(Afrag, Bxfrag)) so D[row=o][col=n]:
//    each lane holds 4 consecutive o -> dwordx4 stores. 8 store instrs/lane/oc
//    instead of 32 scalar (4x fewer VMEM issue slots, 64B segments).

typedef __bf16 bf16x8 __attribute__((ext_vector_type(8)));
typedef float  f32x4  __attribute__((ext_vector_type(4)));

#define SEQLEN  2048
#define D_IN    4096
#define D_OUT   4096
#define RNK     64
#define TN      32     // rows (n) per block
#define BK      128    // K chunk staged in LDS
#define NKB     (D_IN / BK)  // 32
#define BKP     136    // padded LDS row (bf16 elems): stride 272B
#define BXP     72     // padded Bx LDS row: stride 144B

__device__ __forceinline__ bf16x8 cvt8(f32x4 a, f32x4 b) {
    bf16x8 r;
    r[0] = (__bf16)a[0]; r[1] = (__bf16)a[1]; r[2] = (__bf16)a[2]; r[3] = (__bf16)a[3];
    r[4] = (__bf16)b[0]; r[5] = (__bf16)b[1]; r[6] = (__bf16)b[2]; r[7] = (__bf16)b[3];
    return r;
}

__global__ __launch_bounds__(256, 4) void lora_fused(
    const float* __restrict__ x, const int* __restrict__ ids,
    const float* __restrict__ A, const float* __restrict__ Bw,
    float* __restrict__ out)
{
    __shared__ __bf16 xs[2][TN * BKP];  // 2 x 8704 B
    __shared__ __bf16 bxs[TN * BXP];    // 4608 B  (total 22016 B)

    const int tid  = threadIdx.x;
    const int wave = tid >> 6;
    const int lane = tid & 63;
    const int l15  = lane & 15;
    const int quad = lane >> 4;

    // XCD swizzle: round-robin blockIdx->XCD (%8); 2 batches per XCD.
    const int blk  = blockIdx.x;          // 0..1023
    const int slot = blk >> 3;            // 0..127
    const int b    = (blk & 7) * 2 + (slot >> 6);  // 0..15
    const int nt   = slot & 63;           // 0..63

    const int aid = ids[b];
    const float* xb = x   + ((size_t)b * SEQLEN + (size_t)nt * TN) * D_IN;
    float*       ob = out + ((size_t)b * SEQLEN + (size_t)nt * TN) * D_OUT;
    const float* Aq = A  + (size_t)aid * D_OUT * RNK;
    const float* Bq = Bw + (size_t)aid * RNK * D_IN;

    f32x4 zero; zero[0] = zero[1] = zero[2] = zero[3] = 0.0f;

    // ---- Stage 1: Bx[n, r] = sum_k x[n,k] * B[r,k]; wave w owns r-tile w ----
    f32x4 acc[2];   // 2 n-tiles of 16; lane: row=quad*4+j, col(r)=16w+l15
    acc[0] = zero; acc[1] = zero;

    const int srow = tid >> 3;   // 0..31: staging row
    const int sq   = tid & 7;    // 16-float slice of the 128-wide K chunk
    const float* xsrc = xb + (size_t)srow * D_IN + sq * 16;
    const float* bsrc = Bq + (size_t)(wave * 16 + l15) * D_IN + quad * 8;

    f32x4 xpA[4], xpB[4];   // x prefetch, depth 2 (named buffers: rule #20)
    f32x4 bpre[8];          // B prefetch, depth 1

    // Prologue: issue X0, X1, B0; stage X0 into xs[0].
    #pragma unroll
    for (int i = 0; i < 4; ++i)
        xpA[i] = __builtin_nontemporal_load((const f32x4*)(xsrc + i * 4));
    #pragma unroll
    for (int i = 0; i < 4; ++i)
        xpB[i] = __builtin_nontemporal_load((const f32x4*)(xsrc + BK + i * 4));
    #pragma unroll
    for (int s = 0; s < 4; ++s) {
        bpre[2 * s]     = *(const f32x4*)(bsrc + s * 32);
        bpre[2 * s + 1] = *(const f32x4*)(bsrc + s * 32 + 4);
    }
    {
        __bf16* xd = &xs[0][srow * BKP + sq * 16];
        *(bf16x8*)xd       = cvt8(xpA[0], xpA[1]);   // waits X0 (vmcnt(12): X1+B0 newer)
        *(bf16x8*)(xd + 8) = cvt8(xpA[2], xpA[3]);
    }

    // Steady state at iter kb: xs[kb&1]=X_kb staged; XPIN=X_{kb+1} in flight;
    // bpre=B_kb in flight (issued iter kb-1, complete by now).
#define S1_STEP(KB, CUR, XPIN, XPOUT)                                          \
    {                                                                          \
        if ((KB) + 2 < NKB) {                                                  \
            const float* sp_ = xsrc + (size_t)((KB) + 2) * BK;                 \
            _Pragma("unroll")                                                  \
            for (int i = 0; i < 4; ++i)                                        \
                XPOUT[i] = __builtin_nontemporal_load((const f32x4*)(sp_ + i * 4)); \
        }                                                                      \
        bf16x8 bc_[4];  /* cvt B_KB: wait vmcnt(4) (only X_{KB+2} newer) */    \
        _Pragma("unroll")                                                      \
        for (int s = 0; s < 4; ++s) bc_[s] = cvt8(bpre[2 * s], bpre[2 * s + 1]); \
        if ((KB) + 1 < NKB) {  /* issue B_{KB+1} */                            \
            const float* bp_ = bsrc + (size_t)((KB) + 1) * BK;                 \
            _Pragma("unroll")                                                  \
            for (int s = 0; s < 4; ++s) {                                      \
                bpre[2 * s]     = *(const f32x4*)(bp_ + s * 32);               \
                bpre[2 * s + 1] = *(const f32x4*)(bp_ + s * 32 + 4);           \
            }                                                                  \
        }                                                                      \
        asm volatile("s_waitcnt lgkmcnt(0)\n\ts_barrier" ::: "memory");        \
        const __bf16* xc_ = xs[CUR];                                           \
        _Pragma("unroll")                                                      \
        for (int s = 0; s < 4; ++s) {                                          \
            _Pragma("unroll")                                                  \
            for (int t = 0; t < 2; ++t) {                                      \
                bf16x8 af_ = *(const bf16x8*)&xc_[(t * 16 + l15) * BKP + s * 32 + quad * 8]; \
                acc[t] = __builtin_amdgcn_mfma_f32_16x16x32_bf16(af_, bc_[s], acc[t], 0, 0, 0); \
            }                                                                  \
        }                                                                      \
        if ((KB) + 1 < NKB) {  /* stage X_{KB+1}: wait vmcnt(12) */            \
            __bf16* xd_ = &xs[(CUR) ^ 1][srow * BKP + sq * 16];                \
            *(bf16x8*)xd_       = cvt8(XPIN[0], XPIN[1]);                      \
            *(bf16x8*)(xd_ + 8) = cvt8(XPIN[2], XPIN[3]);                      \
        }                                                                      \
    }

    for (int kb = 0; kb < NKB; kb += 2) {
        S1_STEP(kb,     0, xpB, xpA);
        S1_STEP(kb + 1, 1, xpA, xpB);
    }
#undef S1_STEP

    // ---- Bx -> LDS as bf16 (fold exact 1/64 scaling) ----
    #pragma unroll
    for (int t = 0; t < 2; ++t)
        #pragma unroll
        for (int j = 0; j < 4; ++j)
            bxs[(t * 16 + quad * 4 + j) * BXP + wave * 16 + l15] =
                (__bf16)(acc[t][j] * 0.015625f);
    __syncthreads();

    bf16x8 a2[2][2];  // a2[t][s] = Bx[n=16t+l15][r=s*32+quad*8+j]
    #pragma unroll
    for (int t = 0; t < 2; ++t)
        #pragma unroll
        for (int s = 0; s < 2; ++s)
            a2[t][s] = *(const bf16x8*)&bxs[(t * 16 + l15) * BXP + s * 32 + quad * 8];

    // ---- Stage 2: out[n, o] = sum_r Bx[n,r] * A[o,r]; wave w owns o%256 slice ----
    // Swapped operands: acc2 = mfma(Afrag, Bxfrag) -> D[row=o][col=n]; lane
    // (quad,l15) holds j=0..3 -> o = o0+ot*16+quad*4+j (consecutive) at n = t*16+l15.
    for (int oc = 0; oc < 16; ++oc) {
        const int o0 = oc * 256 + wave * 64;
        bf16x8 b2[4][2];  // lane holds A[o=o0+16ot+l15][r=s*32+quad*8+j]
        #pragma unroll
        for (int ot = 0; ot < 4; ++ot) {
            const float* ap = Aq + (size_t)(o0 + ot * 16 + l15) * RNK + quad * 8;
            #pragma unroll
            for (int s = 0; s < 2; ++s) {
                f32x4 a0 = *(const f32x4*)(ap + s * 32);
                f32x4 a1 = *(const f32x4*)(ap + s * 32 + 4);
                b2[ot][s] = cvt8(a0, a1);
            }
        }
        f32x4 acc2[4][2];  // [ot][t]
        #pragma unroll
        for (int ot = 0; ot < 4; ++ot)
            #pragma unroll
            for (int t = 0; t < 2; ++t)
                acc2[ot][t] = zero;
        #pragma unroll
        for (int s = 0; s < 2; ++s)
            #pragma unroll
            for (int ot = 0; ot < 4; ++ot)
                #pragma unroll
                for (int t = 0; t < 2; ++t)
                    acc2[ot][t] = __builtin_amdgcn_mfma_f32_16x16x32_bf16(
                        b2[ot][s], a2[t][s], acc2[ot][t], 0, 0, 0);
        // dwordx4 stores: 16 rows x 64B contiguous per instruction.
        #pragma unroll
        for (int t = 0; t < 2; ++t)
            #pragma unroll
            for (int ot = 0; ot < 4; ++ot)
                *(f32x4*)(ob + (size_t)(t * 16 + l15) * D_OUT + o0 + ot * 16 + quad * 4) =
                    acc2[ot][t];
    }
}

extern "C" void kernel_launch(void* const* d_in, const int* in_sizes, int n_in,
                              void* d_out, int out_size, void* d_ws, size_t ws_size,
                              hipStream_t stream) {
    (void)in_sizes; (void)n_in; (void)d_ws; (void)ws_size; (void)out_size;
    const float* x   = (const float*)d_in[0];
    const int*   ids = (const int*)d_in[1];
    const float* A   = (const float*)d_in[2];
    const float* B   = (const float*)d_in[3];
    float*       out = (float*)d_out;

    dim3 grid(1024), block(256);
    hipLaunchKernelGGL(lora_fused, grid, block, 0, stream, x, ids, A, B, out);
}